// Round 1
// baseline (266.989 us; speedup 1.0000x reference)
//
#include <hip/hip_runtime.h>
#include <hip/hip_bf16.h>
#include <stdint.h>

#define B_ 4
#define S_ 2048
#define H_ 1024

typedef __attribute__((ext_vector_type(4))) float f32x4;
typedef __attribute__((ext_vector_type(8))) short bf16x8;

#define AS1C(p) ((const __attribute__((address_space(1))) void*)(p))
#define AS3(p)  ((__attribute__((address_space(3))) void*)(p))
#define BARRIER() asm volatile("s_barrier" ::: "memory")
#define WAITVM(n) asm volatile("s_waitcnt vmcnt(" #n ")" ::: "memory")

// ------- one-shot prep: convert X, Wq|Wk|Wv, pack biases, zero rsum -------
__global__ __launch_bounds__(256)
void prep_k(const float* __restrict__ X,
            const float* __restrict__ Wq, const float* __restrict__ Wk,
            const float* __restrict__ Wv,
            const float* __restrict__ bq, const float* __restrict__ bk,
            const float* __restrict__ bv,
            __hip_bfloat16* __restrict__ Xb, __hip_bfloat16* __restrict__ Wall,
            float* __restrict__ ball, float* __restrict__ rsum)
{
    const int NX = B_ * S_ * H_ / 4;   // float4 count of X
    const int NW = H_ * H_ / 4;        // float4 count of one W (2^18)
    int i = blockIdx.x * blockDim.x + threadIdx.x;
    if (i < NX + 3 * NW) {
        const float* src; uint64_t* dst; int li;
        if (i < NX) { src = X; dst = (uint64_t*)Xb; li = i; }
        else {
            int j = i - NX;
            int wsel = j / NW; li = j - wsel * NW;
            src = (wsel == 0) ? Wq : (wsel == 1) ? Wk : Wv;
            dst = (uint64_t*)Wall + (size_t)wsel * NW;
        }
        float4 v = ((const float4*)src)[li];
        union { __hip_bfloat16 h[4]; uint64_t u; } o;
        o.h[0] = __float2bfloat16(v.x);
        o.h[1] = __float2bfloat16(v.y);
        o.h[2] = __float2bfloat16(v.z);
        o.h[3] = __float2bfloat16(v.w);
        dst[li] = o.u;
    } else {
        int j = i - (NX + 3 * NW);
        if (j < 3 * H_ / 4) {                    // bias pack (float4)
            int bsel = j >> 8;
            int off  = j & 255;
            const float* src = (bsel == 0) ? bq : (bsel == 1) ? bk : bv;
            ((float4*)ball)[j] = ((const float4*)src)[off];
        } else if (j < 3 * H_ / 4 + B_ * S_ / 4) {   // zero rsum (float4)
            int j2 = j - 3 * H_ / 4;
            ((float4*)rsum)[j2] = make_float4(0.f, 0.f, 0.f, 0.f);
        }
    }
}

// =====================================================================
// 256x256 8-phase counted-vmcnt GEMM (T3+T4+T5 port of the m201 template)
// C[M,N] = scale * (A[M,K] @ B[N,K]^T) [+ bias]
// 8 waves (2M x 4N), per-wave 128x64 output = 8x4 MFMA frags.
// K is consumed in 32-wide slices; LDS = 4-slot ring per operand
// (4 x 256rows x 32cols bf16 = 64 KiB each, 128 KiB total).
// Per phase p (8 phases / 4 slices / 2 K-tiles per iteration):
//   ds_read frags (8 b128 even-p, 4 odd-p; B-frags reused even->odd)
//   stage 1 half-tile = 2 x global_load_lds (slice j0+(p>>1)+3, A on even/B on odd)
//   s_barrier ; setprio(1) ; 16 MFMA ; setprio(0)
//   counted vmcnt(6) on odd phases (tail: 6 -> 4 -> 0) ; s_barrier
// Staging runs 3 slices ahead; vmcnt+barrier is the collective RAW gate.
// XOR chunk swizzle (chunk ^= row&3) on staged source + read addr: the
// 0-bank-conflict scheme from the old kernel, scaled to 64B rows.
// =====================================================================
template<bool OUT_BF16, bool HAS_BIAS, bool V_SPLIT, bool EXP_SUM>
__global__ __launch_bounds__(512, 2)
void gemm256(const __hip_bfloat16* __restrict__ A, int lda, long long aBatch,
             const __hip_bfloat16* __restrict__ B, int ldb, long long bBatch,
             const float* __restrict__ bias,
             void* __restrict__ Cout, int ldc, long long cBatch,
             __hip_bfloat16* __restrict__ vtrans, float* __restrict__ rsum,
             int K, float scale)
{
    __shared__ __hip_bfloat16 lA[4 * 256 * 32];
    __shared__ __hip_bfloat16 lB[4 * 256 * 32];

    const int t  = threadIdx.x;
    const int bz = blockIdx.z;
    A += (long long)bz * aBatch;
    B += (long long)bz * bBatch;
    const int bm = blockIdx.y * 256;
    const int bn = blockIdx.x * 256;

    const int wave = t >> 6;
    const int lane = t & 63;
    const int wm = (wave >> 2) * 128;
    const int wn = (wave & 3) * 64;
    const int lm = lane & 15;
    const int kq = lane >> 4;

    // staging addressing: thread t -> row (l*128 + (t>>2)), swizzled 16B chunk
    const int srow = t >> 2;                       // 0..127
    const int sch  = (t & 3) ^ (srow & 3);         // pre-swizzled source chunk
    const __hip_bfloat16* gA0 = A + (long long)(bm + srow) * lda + sch * 8;
    const __hip_bfloat16* gA1 = gA0 + (long long)128 * lda;
    const __hip_bfloat16* gB0 = B + (long long)(bn + srow) * ldb + sch * 8;
    const __hip_bfloat16* gB1 = gB0 + (long long)128 * ldb;
    __hip_bfloat16* sA = lA + t * 8;               // linear LDS dest (lane*16B)
    __hip_bfloat16* sB = lB + t * 8;

    // LDS read bases: row = w? + frag*16 + lm, phys chunk = kq ^ (lm&3)
    const int rch = (kq ^ (lm & 3)) * 8;
    const __hip_bfloat16* rA = lA + (wm + lm) * 32 + rch;
    const __hip_bfloat16* rB = lB + (wn + lm) * 32 + rch;

    f32x4 acc[8][4] = {};
    bf16x8 bfr[4];

    auto stageA = [&](int js) {
        const int so = (js & 3) * 8192;
        __builtin_amdgcn_global_load_lds(AS1C(gA0 + js * 32), AS3(sA + so), 16, 0, 0);
        __builtin_amdgcn_global_load_lds(AS1C(gA1 + js * 32), AS3(sA + so + 4096), 16, 0, 0);
    };
    auto stageB = [&](int js) {
        const int so = (js & 3) * 8192;
        __builtin_amdgcn_global_load_lds(AS1C(gB0 + js * 32), AS3(sB + so), 16, 0, 0);
        __builtin_amdgcn_global_load_lds(AS1C(gB1 + js * 32), AS3(sB + so + 4096), 16, 0, 0);
    };

    // prologue: slices 0,1,2 staged; wait so slice 0 (oldest 8 loads... keep 8) landed
    stageA(0); stageB(0); stageA(1); stageB(1); stageA(2); stageB(2);
    WAITVM(8);
    BARRIER();

    const int nIter = K >> 7;          // 2 K-tiles (4 slices) per iteration
    for (int i = 0; i < nIter; ++i) {
        const bool lastI = (i == nIter - 1);
        const int j0 = i * 4;
#pragma unroll
        for (int p = 0; p < 8; ++p) {
            const int slot = (p >> 1) & 3;
            const int ch = p & 1;                  // C M-half this phase
            bf16x8 af[4];
#pragma unroll
            for (int mi = 0; mi < 4; ++mi)
                af[mi] = *(const bf16x8*)(rA + slot * 8192 + (ch * 4 + mi) * 512);
            if (ch == 0) {
#pragma unroll
                for (int nj = 0; nj < 4; ++nj)
                    bfr[nj] = *(const bf16x8*)(rB + slot * 8192 + nj * 512);
            }
            if (p < 2 || !lastI) {                 // tail: only slice j0+3 remains
                const int js = j0 + (p >> 1) + 3;
                if (ch == 0) stageA(js); else stageB(js);
            }
            BARRIER();
            __builtin_amdgcn_s_setprio(1);
#pragma unroll
            for (int mi = 0; mi < 4; ++mi)
#pragma unroll
                for (int nj = 0; nj < 4; ++nj)
                    acc[ch * 4 + mi][nj] = __builtin_amdgcn_mfma_f32_16x16x32_bf16(
                        af[mi], bfr[nj], acc[ch * 4 + mi][nj], 0, 0, 0);
            __builtin_amdgcn_s_setprio(0);
            if (ch == 1) {                         // counted gate for next slice
                if (!lastI)      { WAITVM(6); }
                else if (p == 1) { WAITVM(6); }
                else if (p == 3) { WAITVM(4); }
                else if (p == 5) { WAITVM(0); }
            }
            BARRIER();
        }
    }

    // ---------------- epilogue: C/D layout col = lane&15, row = kq*4 + reg ----
    if (EXP_SUM) {
#pragma unroll
        for (int fi = 0; fi < 8; ++fi) {
            const int rowb = bm + wm + fi * 16 + kq * 4;
            float ps[4] = {0.f, 0.f, 0.f, 0.f};
#pragma unroll
            for (int nj = 0; nj < 4; ++nj) {
                const int col = bn + wn + nj * 16 + lm;
#pragma unroll
                for (int r = 0; r < 4; ++r) {
                    float e = __expf(acc[fi][nj][r] * scale);
                    ps[r] += e;
                    ((__hip_bfloat16*)Cout)[(long long)bz * cBatch +
                        (long long)(rowb + r) * ldc + col] = __float2bfloat16(e);
                }
            }
#pragma unroll
            for (int r = 0; r < 4; ++r) {
#pragma unroll
                for (int m = 1; m < 16; m <<= 1)
                    ps[r] += __shfl_xor(ps[r], m);
            }
            if (lm == 0) {
#pragma unroll
                for (int r = 0; r < 4; ++r)
                    atomicAdd(rsum + bz * S_ + rowb + r, ps[r]);
            }
        }
        return;
    }

    const bool vmode = V_SPLIT && (bn >= 2 * H_);
#pragma unroll
    for (int fi = 0; fi < 8; ++fi) {
        const int rowb = bm + wm + fi * 16 + kq * 4;
#pragma unroll
        for (int nj = 0; nj < 4; ++nj) {
            const int col = bn + wn + nj * 16 + lm;
            float bvv = 0.0f;
            if (HAS_BIAS) bvv = bias[col];
            if (!vmode) {
#pragma unroll
                for (int r = 0; r < 4; ++r) {
                    float val = acc[fi][nj][r] * scale + bvv;
                    long long idx = (long long)bz * cBatch + (long long)(rowb + r) * ldc + col;
                    if (OUT_BF16) ((__hip_bfloat16*)Cout)[idx] = __float2bfloat16(val);
                    else          ((float*)Cout)[idx] = val;
                }
            } else {
                // vtrans[b][e][s]: b = rowb>>11, s = rowb&2047 (+r contiguous), e = col-2048
                const long long ebase = (long long)((rowb >> 11) * H_ + col - 2 * H_) * S_;
                union { ushort4 u; __hip_bfloat16 h[4]; } o;
#pragma unroll
                for (int r = 0; r < 4; ++r)
                    o.h[r] = __float2bfloat16(acc[fi][nj][r] + bvv);
                *(ushort4*)(vtrans + ebase + (rowb & 2047)) = o.u;
            }
        }
    }
}

// ------- legacy 128-tile B-transposed GEMM (kept for the PV pass) -------
template<int BN, int MINW, bool OUT_BF16, bool HAS_BIAS, bool V_SPLIT, bool EXP_SUM, bool ROWDIV>
__global__ __launch_bounds__(256, MINW)
void gemm_bt(const __hip_bfloat16* __restrict__ A, int lda, long long aBatch,
             const __hip_bfloat16* __restrict__ B, int ldb, long long bBatch,
             const float* __restrict__ bias,
             void* __restrict__ Cout, int ldc, long long cBatch,
             __hip_bfloat16* __restrict__ vtrans, float* __restrict__ rsum,
             int M, int N, int K, float scale)
{
    constexpr int FJ = BN / 32;
    constexpr int SN = BN / 32;
    __shared__ __hip_bfloat16 lA[128 * 64];
    __shared__ __hip_bfloat16 lB[BN * 64];

    const int t  = threadIdx.x;
    const int bz = blockIdx.z;
    A += (long long)bz * aBatch;
    B += (long long)bz * bBatch;
    const int bm = blockIdx.y * 128;
    const int bn = blockIdx.x * BN;

    const int wave = t >> 6;
    const int lane = t & 63;
    const int wm = (wave & 1) * 64;
    const int wn = (wave >> 1) * (BN / 2);
    const int lm = lane & 15;
    const int kq = lane >> 4;
    const int cro = lm & 7;

    f32x4 acc[4][FJ] = {};

    const int srow = t >> 3;
    const int swz  = ((t & 7) ^ ((t >> 3) & 7)) * 8;
    const __hip_bfloat16* gA = A + (long long)(bm + srow) * lda + swz;
    const __hip_bfloat16* gB = B + (long long)(bn + srow) * ldb + swz;
    __hip_bfloat16* sA = lA + t * 8;
    __hip_bfloat16* sB = lB + t * 8;

    for (int k0 = 0; k0 < K; k0 += 64) {
        __syncthreads();
#pragma unroll
        for (int s = 0; s < 4; ++s)
            __builtin_amdgcn_global_load_lds(AS1C(gA + (long long)s * 32 * lda + k0),
                                             AS3(sA + s * 2048), 16, 0, 0);
#pragma unroll
        for (int s = 0; s < SN; ++s)
            __builtin_amdgcn_global_load_lds(AS1C(gB + (long long)s * 32 * ldb + k0),
                                             AS3(sB + s * 2048), 16, 0, 0);
        __syncthreads();

#pragma unroll
        for (int ks = 0; ks < 2; ++ks) {
            bf16x8 af[4], bfr[FJ];
            const int ch = ((ks * 4 + kq) ^ cro) * 8;
#pragma unroll
            for (int i = 0; i < 4; ++i)
                af[i] = *(const bf16x8*)(lA + (wm + i * 16 + lm) * 64 + ch);
#pragma unroll
            for (int j = 0; j < FJ; ++j)
                bfr[j] = *(const bf16x8*)(lB + (wn + j * 16 + lm) * 64 + ch);
#pragma unroll
            for (int i = 0; i < 4; ++i)
#pragma unroll
                for (int j = 0; j < FJ; ++j)
                    acc[i][j] = __builtin_amdgcn_mfma_f32_16x16x32_bf16(af[i], bfr[j], acc[i][j], 0, 0, 0);
        }
    }

    const bool vmode = V_SPLIT && (bn >= 2 * H_);
    const int r0q = kq * 4;

    if (EXP_SUM) {
#pragma unroll
        for (int i = 0; i < 4; ++i) {
            const int rowb = bm + wm + i * 16 + r0q;
            float ps[4] = {0.f, 0.f, 0.f, 0.f};
#pragma unroll
            for (int j = 0; j < FJ; ++j) {
                const int col = bn + wn + j * 16 + lm;
#pragma unroll
                for (int r = 0; r < 4; ++r) {
                    float e = __expf(acc[i][j][r] * scale);
                    ps[r] += e;
                    ((__hip_bfloat16*)Cout)[(long long)bz * cBatch +
                        (long long)(rowb + r) * ldc + col] = __float2bfloat16(e);
                }
            }
#pragma unroll
            for (int r = 0; r < 4; ++r) {
#pragma unroll
                for (int m = 1; m < 16; m <<= 1)
                    ps[r] += __shfl_xor(ps[r], m);
            }
            if (lm == 0) {
#pragma unroll
                for (int r = 0; r < 4; ++r)
                    atomicAdd(rsum + bz * S_ + rowb + r, ps[r]);
            }
        }
        return;
    }

#pragma unroll
    for (int i = 0; i < 4; ++i) {
        const int rowb = bm + wm + i * 16 + r0q;
        float inv[4];
        if (ROWDIV) {
            float4 rs = *(const float4*)(rsum + bz * S_ + rowb);
            inv[0] = 1.0f / rs.x; inv[1] = 1.0f / rs.y;
            inv[2] = 1.0f / rs.z; inv[3] = 1.0f / rs.w;
        }
#pragma unroll
        for (int j = 0; j < FJ; ++j) {
            const int col = bn + wn + j * 16 + lm;
            float bvv = 0.0f;
            if (HAS_BIAS) bvv = bias[col];
            if (!vmode) {
#pragma unroll
                for (int r = 0; r < 4; ++r) {
                    float val = ROWDIV ? acc[i][j][r] * inv[r]
                                       : acc[i][j][r] * scale + bvv;
                    long long idx = (long long)bz * cBatch + (long long)(rowb + r) * ldc + col;
                    if (OUT_BF16) ((__hip_bfloat16*)Cout)[idx] = __float2bfloat16(val);
                    else          ((float*)Cout)[idx] = val;
                }
            } else {
                const long long ebase = (long long)((rowb >> 11) * H_ + col - 2 * H_) * S_;
                union { ushort4 u; __hip_bfloat16 h[4]; } o;
#pragma unroll
                for (int r = 0; r < 4; ++r)
                    o.h[r] = __float2bfloat16(acc[i][j][r] + bvv);
                *(ushort4*)(vtrans + ebase + (rowb & 2047)) = o.u;
            }
        }
    }
}

// ---------------- launcher ----------------
extern "C" void kernel_launch(void* const* d_in, const int* in_sizes, int n_in,
                              void* d_out, int out_size, void* d_ws, size_t ws_size,
                              hipStream_t stream)
{
    const float* X  = (const float*)d_in[0];
    const float* Wq = (const float*)d_in[1];
    const float* bq = (const float*)d_in[2];
    const float* Wk = (const float*)d_in[3];
    const float* bk = (const float*)d_in[4];
    const float* Wv = (const float*)d_in[5];
    const float* bv = (const float*)d_in[6];
    float* out = (float*)d_out;

    char* w = (char*)d_ws;
    const size_t MB = 1ull << 20;
    // Layout (~80 MB):
    //   [0,16)   Xb          (dead after QKV gemm)
    //   [16,22)  Wall bf16 [3072,1024]   (dead after QKV gemm)
    //   [22,23)  ball fp32 [3072]        (dead after QKV gemm)
    //   [0,32)   sc  exp-scores bf16 [B,S,S]   (overlays dead Xb/Wall/ball)
    //   [32,64)  qk  bf16 [8192,2048]  (Q cols 0..1023, K cols 1024..2047)
    //   [64,80)  vtb bf16 [B,H,S]  (written transposed by QKV epilogue)
    //   [80MB, +32KB) rsum fp32 [B*S]
    __hip_bfloat16* Xb   = (__hip_bfloat16*)(w + 0);
    __hip_bfloat16* Wall = (__hip_bfloat16*)(w + 16 * MB);
    float*          ball = (float*)        (w + 22 * MB);
    __hip_bfloat16* sc   = (__hip_bfloat16*)(w + 0);
    __hip_bfloat16* qk   = (__hip_bfloat16*)(w + 32 * MB);
    __hip_bfloat16* vtb  = (__hip_bfloat16*)(w + 64 * MB);
    float*          rsum = (float*)        (w + 80 * MB);

    // 1. prep (X/W convert + bias pack + rsum zero)
    const int prep_items = B_ * S_ * H_ / 4 + 3 * H_ * H_ / 4 + 3 * H_ / 4 + B_ * S_ / 4;
    prep_k<<<(prep_items + 255) / 256, 256, 0, stream>>>(X, Wq, Wk, Wv, bq, bk, bv,
                                                         Xb, Wall, ball, rsum);

    // 2. fused QKV projection: 256^2 8-phase (384 blocks = 1.5 rounds @1/CU)
    dim3 g1(3 * H_ / 256, (B_ * S_) / 256, 1);   // 12, 32
    gemm256<true, true, true, false><<<g1, 512, 0, stream>>>(
        Xb, H_, 0, Wall, H_, 0, ball, qk, 2 * H_, 0, vtb, nullptr, H_, 1.0f);

    // 3. exp-scores: 256^2 8-phase (8*8*4 = 256 blocks = exactly 1 round @1/CU)
    dim3 g2(S_ / 256, S_ / 256, B_);
    gemm256<true, false, false, true><<<g2, 512, 0, stream>>>(
        qk,      2 * H_, (long long)S_ * 2 * H_,
        qk + H_, 2 * H_, (long long)S_ * 2 * H_,
        nullptr, sc, S_, (long long)S_ * S_, nullptr, rsum, H_, 0.03125f);

    // 4. out[b] = (exp-scores[b] @ vtb[b]^T) / rsum  (legacy kernel; 1024 blocks @4/CU)
    dim3 g3(H_ / 64, S_ / 128, B_);
    gemm_bt<64, 4, false, false, false, false, true><<<g3, 256, 0, stream>>>(
        sc,  S_, (long long)S_ * S_,
        vtb, S_, (long long)H_ * S_,
        nullptr, out, H_, (long long)S_ * H_, nullptr, rsum, S_, H_, S_, 1.0f);
}

// Round 2
// 256.835 us; speedup vs baseline: 1.0395x; 1.0395x over previous
//
#include <hip/hip_runtime.h>
#include <hip/hip_bf16.h>
#include <stdint.h>

#define B_ 4
#define S_ 2048
#define H_ 1024

typedef __attribute__((ext_vector_type(4))) float f32x4;
typedef __attribute__((ext_vector_type(8))) short bf16x8;

#define AS1C(p) ((const __attribute__((address_space(1))) void*)(p))
#define AS3(p)  ((__attribute__((address_space(3))) void*)(p))
#define BARRIER() asm volatile("s_barrier" ::: "memory")
#define WAITVM(n) asm volatile("s_waitcnt vmcnt(" #n ")" ::: "memory")

// ------- one-shot prep: convert X, Wq|Wk|Wv, pack biases, zero rsum -------
__global__ __launch_bounds__(256)
void prep_k(const float* __restrict__ X,
            const float* __restrict__ Wq, const float* __restrict__ Wk,
            const float* __restrict__ Wv,
            const float* __restrict__ bq, const float* __restrict__ bk,
            const float* __restrict__ bv,
            __hip_bfloat16* __restrict__ Xb, __hip_bfloat16* __restrict__ Wall,
            float* __restrict__ ball, float* __restrict__ rsum)
{
    const int NX = B_ * S_ * H_ / 4;   // float4 count of X
    const int NW = H_ * H_ / 4;        // float4 count of one W (2^18)
    int i = blockIdx.x * blockDim.x + threadIdx.x;
    if (i < NX + 3 * NW) {
        const float* src; uint64_t* dst; int li;
        if (i < NX) { src = X; dst = (uint64_t*)Xb; li = i; }
        else {
            int j = i - NX;
            int wsel = j / NW; li = j - wsel * NW;
            src = (wsel == 0) ? Wq : (wsel == 1) ? Wk : Wv;
            dst = (uint64_t*)Wall + (size_t)wsel * NW;
        }
        float4 v = ((const float4*)src)[li];
        union { __hip_bfloat16 h[4]; uint64_t u; } o;
        o.h[0] = __float2bfloat16(v.x);
        o.h[1] = __float2bfloat16(v.y);
        o.h[2] = __float2bfloat16(v.z);
        o.h[3] = __float2bfloat16(v.w);
        dst[li] = o.u;
    } else {
        int j = i - (NX + 3 * NW);
        if (j < 3 * H_ / 4) {                    // bias pack (float4)
            int bsel = j >> 8;
            int off  = j & 255;
            const float* src = (bsel == 0) ? bq : (bsel == 1) ? bk : bv;
            ((float4*)ball)[j] = ((const float4*)src)[off];
        } else if (j < 3 * H_ / 4 + B_ * S_ / 4) {   // zero rsum (float4)
            int j2 = j - 3 * H_ / 4;
            ((float4*)rsum)[j2] = make_float4(0.f, 0.f, 0.f, 0.f);
        }
    }
}

// =====================================================================
// 256x256 8-phase counted-vmcnt GEMM (T3+T4+T5), r2: fixed swizzle + gates.
// C[M,N] = scale * (A[M,K] @ B[N,K]^T) [+ bias]
// 8 waves (2M x 4N), per-wave 128x64 output = 8x4 MFMA frags.
// K consumed in 32-wide slices; LDS = 4-slot ring per operand
// (4 x 256rows x 32cols bf16 = 64 KiB each, 128 KiB total).
// Swizzle (r2 fix): rows are 64B, so banks depend on (r&1); treat row PAIRS
// as 128B lines. Phys 16B chunk c of row r holds logical k-chunk
// c ^ ((r>>1)&3). Read quarter (16 lanes) then sweeps all 8 half-line chunks
// -> start banks {0,4,..,28} each 2x = conflict-free (2-way free, m136).
// Gates (r2 fix, m201 cadence): vmcnt(4) at p==3 and p==7 only
// (slices q+1,q+2 landed; newest slice's 4 loads stay in flight).
// Last iter: vmcnt(0) at p==3, none at p==7. Prologue: 3 slices, vmcnt(4).
// WAR safety: slice q+3 overwrites slot holding slice q-1, whose reads
// finished one barrier-separated pair earlier.
// =====================================================================
template<bool OUT_BF16, bool HAS_BIAS, bool V_SPLIT, bool EXP_SUM>
__global__ __launch_bounds__(512, 2)
void gemm256(const __hip_bfloat16* __restrict__ A, int lda, long long aBatch,
             const __hip_bfloat16* __restrict__ B, int ldb, long long bBatch,
             const float* __restrict__ bias,
             void* __restrict__ Cout, int ldc, long long cBatch,
             __hip_bfloat16* __restrict__ vtrans, float* __restrict__ rsum,
             int K, float scale)
{
    __shared__ __hip_bfloat16 lA[4 * 256 * 32];
    __shared__ __hip_bfloat16 lB[4 * 256 * 32];

    const int t  = threadIdx.x;
    const int bz = blockIdx.z;
    A += (long long)bz * aBatch;
    B += (long long)bz * bBatch;
    const int bm = blockIdx.y * 256;
    const int bn = blockIdx.x * 256;

    const int wave = t >> 6;
    const int lane = t & 63;
    const int wm = (wave >> 2) * 128;
    const int wn = (wave & 3) * 64;
    const int lm = lane & 15;
    const int kq = lane >> 4;

    // staging: thread t -> rows (t>>2) and (t>>2)+128, phys chunk t&3.
    // source chunk = phys ^ ((row>>1)&3)  [row-pair swizzle]
    const int srow = t >> 2;                       // 0..127
    const int sch  = (t & 3) ^ ((srow >> 1) & 3);
    const __hip_bfloat16* gA0 = A + (long long)(bm + srow) * lda + sch * 8;
    const __hip_bfloat16* gA1 = gA0 + (long long)128 * lda;   // row srow+128: same (row>>1)&3? (srow+128)>>1 = srow>>1 + 64, &3 preserved
    const __hip_bfloat16* gB0 = B + (long long)(bn + srow) * ldb + sch * 8;
    const __hip_bfloat16* gB1 = gB0 + (long long)128 * ldb;
    __hip_bfloat16* sA = lA + t * 8;               // linear LDS dest (lane*16B)
    __hip_bfloat16* sB = lB + t * 8;

    // LDS read: row = w? + frag*16 + lm -> (row>>1)&3 == (lm>>1)&3
    // (wm, wn, frag*16 all multiples of 16 -> >>1 multiples of 8)
    const int rch = (kq ^ ((lm >> 1) & 3)) * 8;
    const __hip_bfloat16* rA = lA + (wm + lm) * 32 + rch;
    const __hip_bfloat16* rB = lB + (wn + lm) * 32 + rch;

    f32x4 acc[8][4] = {};
    bf16x8 bfr[4];

    auto stageA = [&](int js) {
        const int so = (js & 3) * 8192;
        __builtin_amdgcn_global_load_lds(AS1C(gA0 + js * 32), AS3(sA + so), 16, 0, 0);
        __builtin_amdgcn_global_load_lds(AS1C(gA1 + js * 32), AS3(sA + so + 4096), 16, 0, 0);
    };
    auto stageB = [&](int js) {
        const int so = (js & 3) * 8192;
        __builtin_amdgcn_global_load_lds(AS1C(gB0 + js * 32), AS3(sB + so), 16, 0, 0);
        __builtin_amdgcn_global_load_lds(AS1C(gB1 + js * 32), AS3(sB + so + 4096), 16, 0, 0);
    };

    // prologue: slices 0,1,2 staged (12 loads); slices 0,1 must land -> vmcnt(4)
    stageA(0); stageB(0); stageA(1); stageB(1); stageA(2); stageB(2);
    WAITVM(4);
    BARRIER();

    const int nIter = K >> 7;          // 4 slices (128 K) per iteration
    for (int i = 0; i < nIter; ++i) {
        const bool lastI = (i == nIter - 1);
        const int j0 = i * 4;
#pragma unroll
        for (int p = 0; p < 8; ++p) {
            const int slot = (p >> 1) & 3;
            const int ch = p & 1;                  // C M-half this phase
            bf16x8 af[4];
#pragma unroll
            for (int mi = 0; mi < 4; ++mi)
                af[mi] = *(const bf16x8*)(rA + slot * 8192 + (ch * 4 + mi) * 512);
            if (ch == 0) {
#pragma unroll
                for (int nj = 0; nj < 4; ++nj)
                    bfr[nj] = *(const bf16x8*)(rB + slot * 8192 + nj * 512);
            }
            if (p < 2 || !lastI) {                 // tail: only slice j0+3 remains
                const int js = j0 + (p >> 1) + 3;
                if (ch == 0) stageA(js); else stageB(js);
            }
            BARRIER();
            __builtin_amdgcn_s_setprio(1);
#pragma unroll
            for (int mi = 0; mi < 4; ++mi)
#pragma unroll
                for (int nj = 0; nj < 4; ++nj)
                    acc[ch * 4 + mi][nj] = __builtin_amdgcn_mfma_f32_16x16x32_bf16(
                        af[mi], bfr[nj], acc[ch * 4 + mi][nj], 0, 0, 0);
            __builtin_amdgcn_s_setprio(0);
            // counted gates, m201 cadence: only at p==3 / p==7
            if (p == 3) {
                if (!lastI) { WAITVM(4); } else { WAITVM(0); }
            } else if (p == 7) {
                if (!lastI) { WAITVM(4); }
            }
            BARRIER();
        }
    }

    // ---------------- epilogue: C/D layout col = lane&15, row = kq*4 + reg ----
    if (EXP_SUM) {
#pragma unroll
        for (int fi = 0; fi < 8; ++fi) {
            const int rowb = bm + wm + fi * 16 + kq * 4;
            float ps[4] = {0.f, 0.f, 0.f, 0.f};
#pragma unroll
            for (int nj = 0; nj < 4; ++nj) {
                const int col = bn + wn + nj * 16 + lm;
#pragma unroll
                for (int r = 0; r < 4; ++r) {
                    float e = __expf(acc[fi][nj][r] * scale);
                    ps[r] += e;
                    ((__hip_bfloat16*)Cout)[(long long)bz * cBatch +
                        (long long)(rowb + r) * ldc + col] = __float2bfloat16(e);
                }
            }
#pragma unroll
            for (int r = 0; r < 4; ++r) {
#pragma unroll
                for (int m = 1; m < 16; m <<= 1)
                    ps[r] += __shfl_xor(ps[r], m);
            }
            if (lm == 0) {
#pragma unroll
                for (int r = 0; r < 4; ++r)
                    atomicAdd(rsum + bz * S_ + rowb + r, ps[r]);
            }
        }
        return;
    }

    const bool vmode = V_SPLIT && (bn >= 2 * H_);
#pragma unroll
    for (int fi = 0; fi < 8; ++fi) {
        const int rowb = bm + wm + fi * 16 + kq * 4;
#pragma unroll
        for (int nj = 0; nj < 4; ++nj) {
            const int col = bn + wn + nj * 16 + lm;
            float bvv = 0.0f;
            if (HAS_BIAS) bvv = bias[col];
            if (!vmode) {
#pragma unroll
                for (int r = 0; r < 4; ++r) {
                    float val = acc[fi][nj][r] * scale + bvv;
                    long long idx = (long long)bz * cBatch + (long long)(rowb + r) * ldc + col;
                    if (OUT_BF16) ((__hip_bfloat16*)Cout)[idx] = __float2bfloat16(val);
                    else          ((float*)Cout)[idx] = val;
                }
            } else {
                // vtrans[b][e][s]: b = rowb>>11, s = rowb&2047 (+r contiguous), e = col-2048
                const long long ebase = (long long)((rowb >> 11) * H_ + col - 2 * H_) * S_;
                union { ushort4 u; __hip_bfloat16 h[4]; } o;
#pragma unroll
                for (int r = 0; r < 4; ++r)
                    o.h[r] = __float2bfloat16(acc[fi][nj][r] + bvv);
                *(ushort4*)(vtrans + ebase + (rowb & 2047)) = o.u;
            }
        }
    }
}

// ------- legacy 128-tile B-transposed GEMM (kept for the PV pass) -------
template<int BN, int MINW, bool OUT_BF16, bool HAS_BIAS, bool V_SPLIT, bool EXP_SUM, bool ROWDIV>
__global__ __launch_bounds__(256, MINW)
void gemm_bt(const __hip_bfloat16* __restrict__ A, int lda, long long aBatch,
             const __hip_bfloat16* __restrict__ B, int ldb, long long bBatch,
             const float* __restrict__ bias,
             void* __restrict__ Cout, int ldc, long long cBatch,
             __hip_bfloat16* __restrict__ vtrans, float* __restrict__ rsum,
             int M, int N, int K, float scale)
{
    constexpr int FJ = BN / 32;
    constexpr int SN = BN / 32;
    __shared__ __hip_bfloat16 lA[128 * 64];
    __shared__ __hip_bfloat16 lB[BN * 64];

    const int t  = threadIdx.x;
    const int bz = blockIdx.z;
    A += (long long)bz * aBatch;
    B += (long long)bz * bBatch;
    const int bm = blockIdx.y * 128;
    const int bn = blockIdx.x * BN;

    const int wave = t >> 6;
    const int lane = t & 63;
    const int wm = (wave & 1) * 64;
    const int wn = (wave >> 1) * (BN / 2);
    const int lm = lane & 15;
    const int kq = lane >> 4;
    const int cro = lm & 7;

    f32x4 acc[4][FJ] = {};

    const int srow = t >> 3;
    const int swz  = ((t & 7) ^ ((t >> 3) & 7)) * 8;
    const __hip_bfloat16* gA = A + (long long)(bm + srow) * lda + swz;
    const __hip_bfloat16* gB = B + (long long)(bn + srow) * ldb + swz;
    __hip_bfloat16* sA = lA + t * 8;
    __hip_bfloat16* sB = lB + t * 8;

    for (int k0 = 0; k0 < K; k0 += 64) {
        __syncthreads();
#pragma unroll
        for (int s = 0; s < 4; ++s)
            __builtin_amdgcn_global_load_lds(AS1C(gA + (long long)s * 32 * lda + k0),
                                             AS3(sA + s * 2048), 16, 0, 0);
#pragma unroll
        for (int s = 0; s < SN; ++s)
            __builtin_amdgcn_global_load_lds(AS1C(gB + (long long)s * 32 * ldb + k0),
                                             AS3(sB + s * 2048), 16, 0, 0);
        __syncthreads();

#pragma unroll
        for (int ks = 0; ks < 2; ++ks) {
            bf16x8 af[4], bfr[FJ];
            const int ch = ((ks * 4 + kq) ^ cro) * 8;
#pragma unroll
            for (int i = 0; i < 4; ++i)
                af[i] = *(const bf16x8*)(lA + (wm + i * 16 + lm) * 64 + ch);
#pragma unroll
            for (int j = 0; j < FJ; ++j)
                bfr[j] = *(const bf16x8*)(lB + (wn + j * 16 + lm) * 64 + ch);
#pragma unroll
            for (int i = 0; i < 4; ++i)
#pragma unroll
                for (int j = 0; j < FJ; ++j)
                    acc[i][j] = __builtin_amdgcn_mfma_f32_16x16x32_bf16(af[i], bfr[j], acc[i][j], 0, 0, 0);
        }
    }

    const bool vmode = V_SPLIT && (bn >= 2 * H_);
    const int r0q = kq * 4;

    if (EXP_SUM) {
#pragma unroll
        for (int i = 0; i < 4; ++i) {
            const int rowb = bm + wm + i * 16 + r0q;
            float ps[4] = {0.f, 0.f, 0.f, 0.f};
#pragma unroll
            for (int j = 0; j < FJ; ++j) {
                const int col = bn + wn + j * 16 + lm;
#pragma unroll
                for (int r = 0; r < 4; ++r) {
                    float e = __expf(acc[i][j][r] * scale);
                    ps[r] += e;
                    ((__hip_bfloat16*)Cout)[(long long)bz * cBatch +
                        (long long)(rowb + r) * ldc + col] = __float2bfloat16(e);
                }
            }
#pragma unroll
            for (int r = 0; r < 4; ++r) {
#pragma unroll
                for (int m = 1; m < 16; m <<= 1)
                    ps[r] += __shfl_xor(ps[r], m);
            }
            if (lm == 0) {
#pragma unroll
                for (int r = 0; r < 4; ++r)
                    atomicAdd(rsum + bz * S_ + rowb + r, ps[r]);
            }
        }
        return;
    }

#pragma unroll
    for (int i = 0; i < 4; ++i) {
        const int rowb = bm + wm + i * 16 + r0q;
        float inv[4];
        if (ROWDIV) {
            float4 rs = *(const float4*)(rsum + bz * S_ + rowb);
            inv[0] = 1.0f / rs.x; inv[1] = 1.0f / rs.y;
            inv[2] = 1.0f / rs.z; inv[3] = 1.0f / rs.w;
        }
#pragma unroll
        for (int j = 0; j < FJ; ++j) {
            const int col = bn + wn + j * 16 + lm;
            float bvv = 0.0f;
            if (HAS_BIAS) bvv = bias[col];
            if (!vmode) {
#pragma unroll
                for (int r = 0; r < 4; ++r) {
                    float val = ROWDIV ? acc[i][j][r] * inv[r]
                                       : acc[i][j][r] * scale + bvv;
                    long long idx = (long long)bz * cBatch + (long long)(rowb + r) * ldc + col;
                    if (OUT_BF16) ((__hip_bfloat16*)Cout)[idx] = __float2bfloat16(val);
                    else          ((float*)Cout)[idx] = val;
                }
            } else {
                const long long ebase = (long long)((rowb >> 11) * H_ + col - 2 * H_) * S_;
                union { ushort4 u; __hip_bfloat16 h[4]; } o;
#pragma unroll
                for (int r = 0; r < 4; ++r)
                    o.h[r] = __float2bfloat16(acc[i][j][r] + bvv);
                *(ushort4*)(vtrans + ebase + (rowb & 2047)) = o.u;
            }
        }
    }
}

// ---------------- launcher ----------------
extern "C" void kernel_launch(void* const* d_in, const int* in_sizes, int n_in,
                              void* d_out, int out_size, void* d_ws, size_t ws_size,
                              hipStream_t stream)
{
    const float* X  = (const float*)d_in[0];
    const float* Wq = (const float*)d_in[1];
    const float* bq = (const float*)d_in[2];
    const float* Wk = (const float*)d_in[3];
    const float* bk = (const float*)d_in[4];
    const float* Wv = (const float*)d_in[5];
    const float* bv = (const float*)d_in[6];
    float* out = (float*)d_out;

    char* w = (char*)d_ws;
    const size_t MB = 1ull << 20;
    // Layout (~80 MB):
    //   [0,16)   Xb          (dead after QKV gemm)
    //   [16,22)  Wall bf16 [3072,1024]   (dead after QKV gemm)
    //   [22,23)  ball fp32 [3072]        (dead after QKV gemm)
    //   [0,32)   sc  exp-scores bf16 [B,S,S]   (overlays dead Xb/Wall/ball)
    //   [32,64)  qk  bf16 [8192,2048]  (Q cols 0..1023, K cols 1024..2047)
    //   [64,80)  vtb bf16 [B,H,S]  (written transposed by QKV epilogue)
    //   [80MB, +32KB) rsum fp32 [B*S]
    __hip_bfloat16* Xb   = (__hip_bfloat16*)(w + 0);
    __hip_bfloat16* Wall = (__hip_bfloat16*)(w + 16 * MB);
    float*          ball = (float*)        (w + 22 * MB);
    __hip_bfloat16* sc   = (__hip_bfloat16*)(w + 0);
    __hip_bfloat16* qk   = (__hip_bfloat16*)(w + 32 * MB);
    __hip_bfloat16* vtb  = (__hip_bfloat16*)(w + 64 * MB);
    float*          rsum = (float*)        (w + 80 * MB);

    // 1. prep (X/W convert + bias pack + rsum zero)
    const int prep_items = B_ * S_ * H_ / 4 + 3 * H_ * H_ / 4 + 3 * H_ / 4 + B_ * S_ / 4;
    prep_k<<<(prep_items + 255) / 256, 256, 0, stream>>>(X, Wq, Wk, Wv, bq, bk, bv,
                                                         Xb, Wall, ball, rsum);

    // 2. fused QKV projection: 256^2 8-phase (384 blocks = 1.5 rounds @1/CU)
    dim3 g1(3 * H_ / 256, (B_ * S_) / 256, 1);   // 12, 32
    gemm256<true, true, true, false><<<g1, 512, 0, stream>>>(
        Xb, H_, 0, Wall, H_, 0, ball, qk, 2 * H_, 0, vtb, nullptr, H_, 1.0f);

    // 3. exp-scores: 256^2 8-phase (8*8*4 = 256 blocks = exactly 1 round @1/CU)
    dim3 g2(S_ / 256, S_ / 256, B_);
    gemm256<true, false, false, true><<<g2, 512, 0, stream>>>(
        qk,      2 * H_, (long long)S_ * 2 * H_,
        qk + H_, 2 * H_, (long long)S_ * 2 * H_,
        nullptr, sc, S_, (long long)S_ * S_, nullptr, rsum, H_, 0.03125f);

    // 4. out[b] = (exp-scores[b] @ vtb[b]^T) / rsum  (legacy kernel; 1024 blocks @4/CU)
    dim3 g3(H_ / 64, S_ / 128, B_);
    gemm_bt<64, 4, false, false, false, false, true><<<g3, 256, 0, stream>>>(
        sc,  S_, (long long)S_ * S_,
        vtb, S_, (long long)H_ * S_,
        nullptr, out, H_, (long long)S_ * H_, nullptr, rsum, S_, H_, S_, 1.0f);
}

// Round 3
// 252.995 us; speedup vs baseline: 1.0553x; 1.0152x over previous
//
#include <hip/hip_runtime.h>
#include <hip/hip_bf16.h>
#include <stdint.h>

#define B_ 4
#define S_ 2048
#define H_ 1024

typedef __attribute__((ext_vector_type(4))) float f32x4;
typedef __attribute__((ext_vector_type(8))) short bf16x8;

#define AS1C(p) ((const __attribute__((address_space(1))) void*)(p))
#define AS3(p)  ((__attribute__((address_space(3))) void*)(p))

// ------- one-shot prep: convert X, Wq|Wk|Wv, pack biases, zero rsum -------
__global__ __launch_bounds__(256)
void prep_k(const float* __restrict__ X,
            const float* __restrict__ Wq, const float* __restrict__ Wk,
            const float* __restrict__ Wv,
            const float* __restrict__ bq, const float* __restrict__ bk,
            const float* __restrict__ bv,
            __hip_bfloat16* __restrict__ Xb, __hip_bfloat16* __restrict__ Wall,
            float* __restrict__ ball, float* __restrict__ rsum)
{
    const int NX = B_ * S_ * H_ / 4;   // float4 count of X
    const int NW = H_ * H_ / 4;        // float4 count of one W (2^18)
    int i = blockIdx.x * blockDim.x + threadIdx.x;
    if (i < NX + 3 * NW) {
        const float* src; uint64_t* dst; int li;
        if (i < NX) { src = X; dst = (uint64_t*)Xb; li = i; }
        else {
            int j = i - NX;
            int wsel = j / NW; li = j - wsel * NW;
            src = (wsel == 0) ? Wq : (wsel == 1) ? Wk : Wv;
            dst = (uint64_t*)Wall + (size_t)wsel * NW;
        }
        float4 v = ((const float4*)src)[li];
        union { __hip_bfloat16 h[4]; uint64_t u; } o;
        o.h[0] = __float2bfloat16(v.x);
        o.h[1] = __float2bfloat16(v.y);
        o.h[2] = __float2bfloat16(v.z);
        o.h[3] = __float2bfloat16(v.w);
        dst[li] = o.u;
    } else {
        int j = i - (NX + 3 * NW);
        if (j < 3 * H_ / 4) {                    // bias pack (float4)
            int bsel = j >> 8;
            int off  = j & 255;
            const float* src = (bsel == 0) ? bq : (bsel == 1) ? bk : bv;
            ((float4*)ball)[j] = ((const float4*)src)[off];
        } else if (j < 3 * H_ / 4 + B_ * S_ / 4) {   // zero rsum (float4)
            int j2 = j - 3 * H_ / 4;
            ((float4*)rsum)[j2] = make_float4(0.f, 0.f, 0.f, 0.f);
        }
    }
}

// =====================================================================
// 256-row 2-phase double-buffered GEMM (T3-minimum schedule, proven at
// this exact shape: 256^2 / K=1024 / 8 waves = 655-682 TF, m230/m248v2).
// C[M,N] = scale * (A[M,K] @ B[N,K]^T)
// BM=256 fixed, BN in {256,128}; 8 waves (2M x 4N), per-wave 128 x BN/4.
// Per 64-K tile:
//   stage(buf^1, next tile)   <- issued BEFORE compute (HBM hides under MFMA)
//   ds_read cur buf + 64*FJ/4... MFMAs
//   __syncthreads()           <- vmcnt(0)+lgkmcnt(0)+barrier: ONE per tile
// Fragment geometry + chunk-XOR swizzle identical to the r0-proven legacy
// kernel (64-col rows, phys chunk = (ks*4+kq) ^ (lm&7)): 0 bank conflicts.
// LDS: 2 x (256 + BN) x 64 x 2B = 128 KB (BN=256) / 96 KB (BN=128).
// EXP_SUM: store exp(scale*acc) bf16 + atomicAdd row sums (scores pass).
// ROWDIV : multiply by 1/rsum[row], fp32 out (PV pass).
// =====================================================================
template<int BN, bool OUT_BF16, bool EXP_SUM, bool ROWDIV>
__global__ __launch_bounds__(512, 2)
void gemm2ph(const __hip_bfloat16* __restrict__ A, int lda, long long aBatch,
             const __hip_bfloat16* __restrict__ B, int ldb, long long bBatch,
             void* __restrict__ Cout, int ldc, long long cBatch,
             float* __restrict__ rsum, int K, float scale)
{
    constexpr int FJ = BN / 64;            // per-wave N frags (4 or 2)
    constexpr int GB = BN / 64;            // B-gloads per tile (4 or 2)
    __shared__ __hip_bfloat16 lA[2 * 256 * 64];
    __shared__ __hip_bfloat16 lB[2 * BN * 64];

    const int t  = threadIdx.x;
    const int bz = blockIdx.z;
    A += (long long)bz * aBatch;
    B += (long long)bz * bBatch;
    const int bm = blockIdx.y * 256;
    const int bn = blockIdx.x * BN;

    const int wave = t >> 6;
    const int lane = t & 63;
    const int wm = (wave >> 2) * 128;
    const int wn = (wave & 3) * (BN / 4);
    const int lm = lane & 15;
    const int kq = lane >> 4;
    const int cro = lm & 7;

    // staging: thread t -> row srow (+g*64), swizzled 16B chunk of the 64-col row
    const int srow = t >> 3;               // 0..63
    const int swz  = ((t & 7) ^ (srow & 7)) * 8;
    const __hip_bfloat16* gA = A + (long long)(bm + srow) * lda + swz;
    const __hip_bfloat16* gB = B + (long long)(bn + srow) * ldb + swz;

    f32x4 acc[8][FJ] = {};

    auto stage = [&](int buf, int k0) {
        __hip_bfloat16* dA = lA + buf * (256 * 64) + t * 8;
        __hip_bfloat16* dB = lB + buf * (BN * 64) + t * 8;
#pragma unroll
        for (int g = 0; g < 4; ++g)
            __builtin_amdgcn_global_load_lds(AS1C(gA + (long long)g * 64 * lda + k0),
                                             AS3(dA + g * 4096), 16, 0, 0);
#pragma unroll
        for (int g = 0; g < GB; ++g)
            __builtin_amdgcn_global_load_lds(AS1C(gB + (long long)g * 64 * ldb + k0),
                                             AS3(dB + g * 4096), 16, 0, 0);
    };

    stage(0, 0);
    __syncthreads();

    const int nT = K >> 6;
    int buf = 0;
    for (int tt = 0; tt < nT; ++tt) {
        if (tt + 1 < nT) stage(buf ^ 1, (tt + 1) * 64);
        const __hip_bfloat16* cA = lA + buf * (256 * 64) + (wm + lm) * 64;
        const __hip_bfloat16* cB = lB + buf * (BN * 64) + (wn + lm) * 64;
#pragma unroll
        for (int ks = 0; ks < 2; ++ks) {
            const int ch = ((ks * 4 + kq) ^ cro) * 8;
            bf16x8 af[8], bfr[FJ];
#pragma unroll
            for (int i = 0; i < 8; ++i)
                af[i] = *(const bf16x8*)(cA + i * 16 * 64 + ch);
#pragma unroll
            for (int j = 0; j < FJ; ++j)
                bfr[j] = *(const bf16x8*)(cB + j * 16 * 64 + ch);
#pragma unroll
            for (int i = 0; i < 8; ++i)
#pragma unroll
                for (int j = 0; j < FJ; ++j)
                    acc[i][j] = __builtin_amdgcn_mfma_f32_16x16x32_bf16(
                        af[i], bfr[j], acc[i][j], 0, 0, 0);
        }
        __syncthreads();
        buf ^= 1;
    }

    // ---------------- epilogue: C/D layout col = lane&15, row = kq*4 + reg ----
    if (EXP_SUM) {
#pragma unroll
        for (int fi = 0; fi < 8; ++fi) {
            const int rowb = bm + wm + fi * 16 + kq * 4;
            float ps[4] = {0.f, 0.f, 0.f, 0.f};
#pragma unroll
            for (int nj = 0; nj < FJ; ++nj) {
                const int col = bn + wn + nj * 16 + lm;
#pragma unroll
                for (int r = 0; r < 4; ++r) {
                    float e = __expf(acc[fi][nj][r] * scale);
                    ps[r] += e;
                    ((__hip_bfloat16*)Cout)[(long long)bz * cBatch +
                        (long long)(rowb + r) * ldc + col] = __float2bfloat16(e);
                }
            }
#pragma unroll
            for (int r = 0; r < 4; ++r) {
#pragma unroll
                for (int m = 1; m < 16; m <<= 1)
                    ps[r] += __shfl_xor(ps[r], m);
            }
            if (lm == 0) {
#pragma unroll
                for (int r = 0; r < 4; ++r)
                    atomicAdd(rsum + bz * S_ + rowb + r, ps[r]);
            }
        }
        return;
    }

#pragma unroll
    for (int fi = 0; fi < 8; ++fi) {
        const int rowb = bm + wm + fi * 16 + kq * 4;
        float inv[4];
        if (ROWDIV) {
            float4 rs = *(const float4*)(rsum + bz * S_ + rowb);
            inv[0] = 1.0f / rs.x; inv[1] = 1.0f / rs.y;
            inv[2] = 1.0f / rs.z; inv[3] = 1.0f / rs.w;
        }
#pragma unroll
        for (int nj = 0; nj < FJ; ++nj) {
            const int col = bn + wn + nj * 16 + lm;
#pragma unroll
            for (int r = 0; r < 4; ++r) {
                float val = ROWDIV ? acc[fi][nj][r] * inv[r] : acc[fi][nj][r] * scale;
                long long idx = (long long)bz * cBatch + (long long)(rowb + r) * ldc + col;
                if (OUT_BF16) ((__hip_bfloat16*)Cout)[idx] = __float2bfloat16(val);
                else          ((float*)Cout)[idx] = val;
            }
        }
    }
}

// ------- legacy 128-tile B-transposed GEMM (QKV pass — r0-proven) -------
template<int BN, int MINW, bool OUT_BF16, bool HAS_BIAS, bool V_SPLIT, bool EXP_SUM, bool ROWDIV>
__global__ __launch_bounds__(256, MINW)
void gemm_bt(const __hip_bfloat16* __restrict__ A, int lda, long long aBatch,
             const __hip_bfloat16* __restrict__ B, int ldb, long long bBatch,
             const float* __restrict__ bias,
             void* __restrict__ Cout, int ldc, long long cBatch,
             __hip_bfloat16* __restrict__ vtrans, float* __restrict__ rsum,
             int M, int N, int K, float scale)
{
    constexpr int FJ = BN / 32;
    constexpr int SN = BN / 32;
    __shared__ __hip_bfloat16 lA[128 * 64];
    __shared__ __hip_bfloat16 lB[BN * 64];

    const int t  = threadIdx.x;
    const int bz = blockIdx.z;
    A += (long long)bz * aBatch;
    B += (long long)bz * bBatch;
    const int bm = blockIdx.y * 128;
    const int bn = blockIdx.x * BN;

    const int wave = t >> 6;
    const int lane = t & 63;
    const int wm = (wave & 1) * 64;
    const int wn = (wave >> 1) * (BN / 2);
    const int lm = lane & 15;
    const int kq = lane >> 4;
    const int cro = lm & 7;

    f32x4 acc[4][FJ] = {};

    const int srow = t >> 3;
    const int swz  = ((t & 7) ^ ((t >> 3) & 7)) * 8;
    const __hip_bfloat16* gA = A + (long long)(bm + srow) * lda + swz;
    const __hip_bfloat16* gB = B + (long long)(bn + srow) * ldb + swz;
    __hip_bfloat16* sA = lA + t * 8;
    __hip_bfloat16* sB = lB + t * 8;

    for (int k0 = 0; k0 < K; k0 += 64) {
        __syncthreads();
#pragma unroll
        for (int s = 0; s < 4; ++s)
            __builtin_amdgcn_global_load_lds(AS1C(gA + (long long)s * 32 * lda + k0),
                                             AS3(sA + s * 2048), 16, 0, 0);
#pragma unroll
        for (int s = 0; s < SN; ++s)
            __builtin_amdgcn_global_load_lds(AS1C(gB + (long long)s * 32 * ldb + k0),
                                             AS3(sB + s * 2048), 16, 0, 0);
        __syncthreads();

#pragma unroll
        for (int ks = 0; ks < 2; ++ks) {
            bf16x8 af[4], bfr[FJ];
            const int ch = ((ks * 4 + kq) ^ cro) * 8;
#pragma unroll
            for (int i = 0; i < 4; ++i)
                af[i] = *(const bf16x8*)(lA + (wm + i * 16 + lm) * 64 + ch);
#pragma unroll
            for (int j = 0; j < FJ; ++j)
                bfr[j] = *(const bf16x8*)(lB + (wn + j * 16 + lm) * 64 + ch);
#pragma unroll
            for (int i = 0; i < 4; ++i)
#pragma unroll
                for (int j = 0; j < FJ; ++j)
                    acc[i][j] = __builtin_amdgcn_mfma_f32_16x16x32_bf16(af[i], bfr[j], acc[i][j], 0, 0, 0);
        }
    }

    const bool vmode = V_SPLIT && (bn >= 2 * H_);
    const int r0q = kq * 4;

    if (EXP_SUM) {
#pragma unroll
        for (int i = 0; i < 4; ++i) {
            const int rowb = bm + wm + i * 16 + r0q;
            float ps[4] = {0.f, 0.f, 0.f, 0.f};
#pragma unroll
            for (int j = 0; j < FJ; ++j) {
                const int col = bn + wn + j * 16 + lm;
#pragma unroll
                for (int r = 0; r < 4; ++r) {
                    float e = __expf(acc[i][j][r] * scale);
                    ps[r] += e;
                    ((__hip_bfloat16*)Cout)[(long long)bz * cBatch +
                        (long long)(rowb + r) * ldc + col] = __float2bfloat16(e);
                }
            }
#pragma unroll
            for (int r = 0; r < 4; ++r) {
#pragma unroll
                for (int m = 1; m < 16; m <<= 1)
                    ps[r] += __shfl_xor(ps[r], m);
            }
            if (lm == 0) {
#pragma unroll
                for (int r = 0; r < 4; ++r)
                    atomicAdd(rsum + bz * S_ + rowb + r, ps[r]);
            }
        }
        return;
    }

#pragma unroll
    for (int i = 0; i < 4; ++i) {
        const int rowb = bm + wm + i * 16 + r0q;
        float inv[4];
        if (ROWDIV) {
            float4 rs = *(const float4*)(rsum + bz * S_ + rowb);
            inv[0] = 1.0f / rs.x; inv[1] = 1.0f / rs.y;
            inv[2] = 1.0f / rs.z; inv[3] = 1.0f / rs.w;
        }
#pragma unroll
        for (int j = 0; j < FJ; ++j) {
            const int col = bn + wn + j * 16 + lm;
            float bvv = 0.0f;
            if (HAS_BIAS) bvv = bias[col];
            if (!vmode) {
#pragma unroll
                for (int r = 0; r < 4; ++r) {
                    float val = ROWDIV ? acc[i][j][r] * inv[r]
                                       : acc[i][j][r] * scale + bvv;
                    long long idx = (long long)bz * cBatch + (long long)(rowb + r) * ldc + col;
                    if (OUT_BF16) ((__hip_bfloat16*)Cout)[idx] = __float2bfloat16(val);
                    else          ((float*)Cout)[idx] = val;
                }
            } else {
                // vtrans[b][e][s]: b = rowb>>11, s = rowb&2047 (+r contiguous), e = col-2048
                const long long ebase = (long long)((rowb >> 11) * H_ + col - 2 * H_) * S_;
                union { ushort4 u; __hip_bfloat16 h[4]; } o;
#pragma unroll
                for (int r = 0; r < 4; ++r)
                    o.h[r] = __float2bfloat16(acc[i][j][r] + bvv);
                *(ushort4*)(vtrans + ebase + (rowb & 2047)) = o.u;
            }
        }
    }
}

// ---------------- launcher ----------------
extern "C" void kernel_launch(void* const* d_in, const int* in_sizes, int n_in,
                              void* d_out, int out_size, void* d_ws, size_t ws_size,
                              hipStream_t stream)
{
    const float* X  = (const float*)d_in[0];
    const float* Wq = (const float*)d_in[1];
    const float* bq = (const float*)d_in[2];
    const float* Wk = (const float*)d_in[3];
    const float* bk = (const float*)d_in[4];
    const float* Wv = (const float*)d_in[5];
    const float* bv = (const float*)d_in[6];
    float* out = (float*)d_out;

    char* w = (char*)d_ws;
    const size_t MB = 1ull << 20;
    // Layout (~80 MB):
    //   [0,16)   Xb          (dead after QKV gemm)
    //   [16,22)  Wall bf16 [3072,1024]   (dead after QKV gemm)
    //   [22,23)  ball fp32 [3072]        (dead after QKV gemm)
    //   [0,32)   sc  exp-scores bf16 [B,S,S]   (overlays dead Xb/Wall/ball)
    //   [32,64)  qk  bf16 [8192,2048]  (Q cols 0..1023, K cols 1024..2047)
    //   [64,80)  vtb bf16 [B,H,S]  (written transposed by QKV epilogue)
    //   [80MB, +32KB) rsum fp32 [B*S]
    __hip_bfloat16* Xb   = (__hip_bfloat16*)(w + 0);
    __hip_bfloat16* Wall = (__hip_bfloat16*)(w + 16 * MB);
    float*          ball = (float*)        (w + 22 * MB);
    __hip_bfloat16* sc   = (__hip_bfloat16*)(w + 0);
    __hip_bfloat16* qk   = (__hip_bfloat16*)(w + 32 * MB);
    __hip_bfloat16* vtb  = (__hip_bfloat16*)(w + 64 * MB);
    float*          rsum = (float*)        (w + 80 * MB);

    // 1. prep (X/W convert + bias pack + rsum zero)
    const int prep_items = B_ * S_ * H_ / 4 + 3 * H_ * H_ / 4 + 3 * H_ / 4 + B_ * S_ / 4;
    prep_k<<<(prep_items + 255) / 256, 256, 0, stream>>>(X, Wq, Wk, Wv, bq, bk, bv,
                                                         Xb, Wall, ball, rsum);

    // 2. fused QKV projection: legacy 128x128 (1536 blocks = 2 exact rounds @3/CU)
    dim3 g1(3 * H_ / 128, (B_ * S_) / 128, 1);
    gemm_bt<128, 1, true, true, true, false, false><<<g1, 256, 0, stream>>>(
        Xb, H_, 0, Wall, H_, 0, ball, qk, 2 * H_, 0, vtb, nullptr,
        B_ * S_, 3 * H_, H_, 1.0f);

    // 3. exp-scores: 2-phase 256x256 (8*8*4 = 256 blocks = exactly 1 round @1/CU)
    dim3 g2(S_ / 256, S_ / 256, B_);
    gemm2ph<256, true, true, false><<<g2, 512, 0, stream>>>(
        qk,      2 * H_, (long long)S_ * 2 * H_,
        qk + H_, 2 * H_, (long long)S_ * 2 * H_,
        sc, S_, (long long)S_ * S_, rsum, H_, 0.03125f);

    // 4. out = (exp-scores @ vtb^T) / rsum: 2-phase 256x128 (8*8*4 = 256 blocks, 1 round)
    dim3 g3(H_ / 128, S_ / 256, B_);
    gemm2ph<128, false, false, true><<<g3, 512, 0, stream>>>(
        sc,  S_, (long long)S_ * S_,
        vtb, S_, (long long)H_ * S_,
        out, H_, (long long)S_ * H_, rsum, S_, 1.0f);
}

// Round 4
// 249.376 us; speedup vs baseline: 1.0706x; 1.0145x over previous
//
#include <hip/hip_runtime.h>
#include <hip/hip_bf16.h>
#include <stdint.h>

#define B_ 4
#define S_ 2048
#define H_ 1024

typedef __attribute__((ext_vector_type(4))) float f32x4;
typedef __attribute__((ext_vector_type(8))) short bf16x8;

#define AS1C(p) ((const __attribute__((address_space(1))) void*)(p))
#define AS3(p)  ((__attribute__((address_space(3))) void*)(p))

// ------- one-shot prep: convert X, Wq|Wk|Wv, pack biases, zero rsum -------
// r4: grid-stride @2048 blocks (G11) — the old 11264-block shape measured
// ~1.4 TB/s; this isolates whether prep was the mystery ~45 us.
__global__ __launch_bounds__(256)
void prep_k(const float* __restrict__ X,
            const float* __restrict__ Wq, const float* __restrict__ Wk,
            const float* __restrict__ Wv,
            const float* __restrict__ bq, const float* __restrict__ bk,
            const float* __restrict__ bv,
            __hip_bfloat16* __restrict__ Xb, __hip_bfloat16* __restrict__ Wall,
            float* __restrict__ ball, float* __restrict__ rsum)
{
    const int NX = B_ * S_ * H_ / 4;   // float4 count of X
    const int NW = H_ * H_ / 4;        // float4 count of one W (2^18)
    const int TOT = NX + 3 * NW + 3 * H_ / 4 + B_ * S_ / 4;
    const int stride = gridDim.x * blockDim.x;
    for (int i = blockIdx.x * blockDim.x + threadIdx.x; i < TOT; i += stride) {
        if (i < NX + 3 * NW) {
            const float* src; uint64_t* dst; int li;
            if (i < NX) { src = X; dst = (uint64_t*)Xb; li = i; }
            else {
                int j = i - NX;
                int wsel = j / NW; li = j - wsel * NW;
                src = (wsel == 0) ? Wq : (wsel == 1) ? Wk : Wv;
                dst = (uint64_t*)Wall + (size_t)wsel * NW;
            }
            float4 v = ((const float4*)src)[li];
            union { __hip_bfloat16 h[4]; uint64_t u; } o;
            o.h[0] = __float2bfloat16(v.x);
            o.h[1] = __float2bfloat16(v.y);
            o.h[2] = __float2bfloat16(v.z);
            o.h[3] = __float2bfloat16(v.w);
            dst[li] = o.u;
        } else {
            int j = i - (NX + 3 * NW);
            if (j < 3 * H_ / 4) {                    // bias pack (float4)
                int bsel = j >> 8;
                int off  = j & 255;
                const float* src = (bsel == 0) ? bq : (bsel == 1) ? bk : bv;
                ((float4*)ball)[j] = ((const float4*)src)[off];
            } else {                                  // zero rsum (float4)
                int j2 = j - 3 * H_ / 4;
                ((float4*)rsum)[j2] = make_float4(0.f, 0.f, 0.f, 0.f);
            }
        }
    }
}

// ------- B-transposed bf16 GEMM, 16x16x32 MFMA, BK=64, single-buffer -------
// C[M,N] = scale * (A[M,K] @ B[N,K]^T) + bias[N]
// 128xBN block tile, 4 waves (2x2), wave tile 64 x BN/2.
// XOR chunk swizzle on staging+read: 0 LDS bank conflicts (r3-verified).
// r4: T1 chunked XCD swizzle (bijective, requires nwg%8==0 — guarded):
//     tile = (orig%8)*(nwg/8) + orig/8  ->  each XCD owns a contiguous
//     tile chunk; panel footprint/XCD drops 17-34MB -> 6-8MB (vs 4MB L2).
template<int BN, int MINW, bool OUT_BF16, bool HAS_BIAS, bool V_SPLIT, bool EXP_SUM, bool ROWDIV>
__global__ __launch_bounds__(256, MINW)
void gemm_bt(const __hip_bfloat16* __restrict__ A, int lda, long long aBatch,
             const __hip_bfloat16* __restrict__ B, int ldb, long long bBatch,
             const float* __restrict__ bias,
             void* __restrict__ Cout, int ldc, long long cBatch,
             __hip_bfloat16* __restrict__ vtrans, float* __restrict__ rsum,
             int M, int N, int K, float scale)
{
    constexpr int FJ = BN / 32;        // B-frags per wave (16-col units)
    constexpr int SN = BN / 32;        // B staging steps (32 rows each)
    __shared__ __hip_bfloat16 lA[128 * 64];
    __shared__ __hip_bfloat16 lB[BN * 64];

    const int t  = threadIdx.x;

    // --- T1 chunked XCD swizzle (bijective when nwg%8==0) ---
    const int gx = gridDim.x, gy = gridDim.y;
    int flat = (blockIdx.z * gy + blockIdx.y) * gx + blockIdx.x;
    const int nwg = gx * gy * (int)gridDim.z;
    if ((nwg & 7) == 0)
        flat = (flat & 7) * (nwg >> 3) + (flat >> 3);
    const int bxi = flat % gx;
    const int rem = flat / gx;
    const int byi = rem % gy;
    const int bz  = rem / gy;

    A += (long long)bz * aBatch;
    B += (long long)bz * bBatch;
    const int bm = byi * 128;
    const int bn = bxi * BN;

    const int wave = t >> 6;
    const int lane = t & 63;
    const int wm = (wave & 1) * 64;
    const int wn = (wave >> 1) * (BN / 2);
    const int lm = lane & 15;
    const int kq = lane >> 4;
    const int cro = lm & 7;

    f32x4 acc[4][FJ] = {};

    const int srow = t >> 3;                         // 0..31
    const int swz  = ((t & 7) ^ ((t >> 3) & 7)) * 8;
    const __hip_bfloat16* gA = A + (long long)(bm + srow) * lda + swz;
    const __hip_bfloat16* gB = B + (long long)(bn + srow) * ldb + swz;
    __hip_bfloat16* sA = lA + t * 8;
    __hip_bfloat16* sB = lB + t * 8;

    for (int k0 = 0; k0 < K; k0 += 64) {
        __syncthreads();
#pragma unroll
        for (int s = 0; s < 4; ++s)
            __builtin_amdgcn_global_load_lds(AS1C(gA + (long long)s * 32 * lda + k0),
                                             AS3(sA + s * 2048), 16, 0, 0);
#pragma unroll
        for (int s = 0; s < SN; ++s)
            __builtin_amdgcn_global_load_lds(AS1C(gB + (long long)s * 32 * ldb + k0),
                                             AS3(sB + s * 2048), 16, 0, 0);
        __syncthreads();

#pragma unroll
        for (int ks = 0; ks < 2; ++ks) {
            bf16x8 af[4], bfr[FJ];
            const int ch = ((ks * 4 + kq) ^ cro) * 8;
#pragma unroll
            for (int i = 0; i < 4; ++i)
                af[i] = *(const bf16x8*)(lA + (wm + i * 16 + lm) * 64 + ch);
#pragma unroll
            for (int j = 0; j < FJ; ++j)
                bfr[j] = *(const bf16x8*)(lB + (wn + j * 16 + lm) * 64 + ch);
#pragma unroll
            for (int i = 0; i < 4; ++i)
#pragma unroll
                for (int j = 0; j < FJ; ++j)
                    acc[i][j] = __builtin_amdgcn_mfma_f32_16x16x32_bf16(af[i], bfr[j], acc[i][j], 0, 0, 0);
        }
    }

    // epilogue: C/D layout col = lane&15, row = (lane>>4)*4 + reg  [m89]
    const bool vmode = V_SPLIT && (bn >= 2 * H_);
    const int r0q = kq * 4;

    if (EXP_SUM) {
#pragma unroll
        for (int i = 0; i < 4; ++i) {
            const int rowb = bm + wm + i * 16 + r0q;
            float ps[4] = {0.f, 0.f, 0.f, 0.f};
#pragma unroll
            for (int j = 0; j < FJ; ++j) {
                const int col = bn + wn + j * 16 + lm;
#pragma unroll
                for (int r = 0; r < 4; ++r) {
                    float e = __expf(acc[i][j][r] * scale);
                    ps[r] += e;
                    ((__hip_bfloat16*)Cout)[(long long)bz * cBatch +
                        (long long)(rowb + r) * ldc + col] = __float2bfloat16(e);
                }
            }
#pragma unroll
            for (int r = 0; r < 4; ++r) {
#pragma unroll
                for (int m = 1; m < 16; m <<= 1)
                    ps[r] += __shfl_xor(ps[r], m);
            }
            if (lm == 0) {
#pragma unroll
                for (int r = 0; r < 4; ++r)
                    atomicAdd(rsum + bz * S_ + rowb + r, ps[r]);
            }
        }
        return;
    }

#pragma unroll
    for (int i = 0; i < 4; ++i) {
        const int rowb = bm + wm + i * 16 + r0q;
        float inv[4];
        if (ROWDIV) {
            float4 rs = *(const float4*)(rsum + bz * S_ + rowb);
            inv[0] = 1.0f / rs.x; inv[1] = 1.0f / rs.y;
            inv[2] = 1.0f / rs.z; inv[3] = 1.0f / rs.w;
        }
#pragma unroll
        for (int j = 0; j < FJ; ++j) {
            const int col = bn + wn + j * 16 + lm;
            float bvv = 0.0f;
            if (HAS_BIAS) bvv = bias[col];
            if (!vmode) {
#pragma unroll
                for (int r = 0; r < 4; ++r) {
                    float val = ROWDIV ? acc[i][j][r] * inv[r]
                                       : acc[i][j][r] * scale + bvv;
                    long long idx = (long long)bz * cBatch + (long long)(rowb + r) * ldc + col;
                    if (OUT_BF16) ((__hip_bfloat16*)Cout)[idx] = __float2bfloat16(val);
                    else          ((float*)Cout)[idx] = val;
                }
            } else {
                // vtrans[b][e][s]: b = rowb>>11, s = rowb&2047 (+r contiguous), e = col-2048
                const long long ebase = (long long)((rowb >> 11) * H_ + col - 2 * H_) * S_;
                union { ushort4 u; __hip_bfloat16 h[4]; } o;
#pragma unroll
                for (int r = 0; r < 4; ++r)
                    o.h[r] = __float2bfloat16(acc[i][j][r] + bvv);
                *(ushort4*)(vtrans + ebase + (rowb & 2047)) = o.u;
            }
        }
    }
}

// ---------------- launcher ----------------
extern "C" void kernel_launch(void* const* d_in, const int* in_sizes, int n_in,
                              void* d_out, int out_size, void* d_ws, size_t ws_size,
                              hipStream_t stream)
{
    const float* X  = (const float*)d_in[0];
    const float* Wq = (const float*)d_in[1];
    const float* bq = (const float*)d_in[2];
    const float* Wk = (const float*)d_in[3];
    const float* bk = (const float*)d_in[4];
    const float* Wv = (const float*)d_in[5];
    const float* bv = (const float*)d_in[6];
    float* out = (float*)d_out;

    char* w = (char*)d_ws;
    const size_t MB = 1ull << 20;
    // Layout (~80 MB):
    //   [0,16)   Xb          (dead after QKV gemm)
    //   [16,22)  Wall bf16 [3072,1024]   (dead after QKV gemm)
    //   [22,23)  ball fp32 [3072]        (dead after QKV gemm)
    //   [0,32)   sc  exp-scores bf16 [B,S,S]   (overlays dead Xb/Wall/ball)
    //   [32,64)  qk  bf16 [8192,2048]  (Q cols 0..1023, K cols 1024..2047)
    //   [64,80)  vtb bf16 [B,H,S]  (written transposed by QKV epilogue)
    //   [80MB, +32KB) rsum fp32 [B*S]
    __hip_bfloat16* Xb   = (__hip_bfloat16*)(w + 0);
    __hip_bfloat16* Wall = (__hip_bfloat16*)(w + 16 * MB);
    float*          ball = (float*)        (w + 22 * MB);
    __hip_bfloat16* sc   = (__hip_bfloat16*)(w + 0);
    __hip_bfloat16* qk   = (__hip_bfloat16*)(w + 32 * MB);
    __hip_bfloat16* vtb  = (__hip_bfloat16*)(w + 64 * MB);
    float*          rsum = (float*)        (w + 80 * MB);

    // 1. prep (X/W convert + bias pack + rsum zero) — grid-stride @2048 blocks
    prep_k<<<2048, 256, 0, stream>>>(X, Wq, Wk, Wv, bq, bk, bv,
                                     Xb, Wall, ball, rsum);

    // 2. fused QKV projection (1536 blocks = 2 exact rounds @3/CU)
    dim3 g1(3 * H_ / 128, (B_ * S_) / 128, 1);
    gemm_bt<128, 1, true, true, true, false, false><<<g1, 256, 0, stream>>>(
        Xb, H_, 0, Wall, H_, 0, ball, qk, 2 * H_, 0, vtb, nullptr,
        B_ * S_, 3 * H_, H_, 1.0f);

    // 3. exp-scores (1024 blocks; MINW=4 -> 4 blocks/CU -> exactly 1 round)
    dim3 g2(S_ / 128, S_ / 128, B_);
    gemm_bt<128, 4, true, false, false, true, false><<<g2, 256, 0, stream>>>(
        qk,      2 * H_, (long long)S_ * 2 * H_,
        qk + H_, 2 * H_, (long long)S_ * 2 * H_,
        nullptr, sc, S_, (long long)S_ * S_, nullptr, rsum, S_, S_, H_, 0.03125f);

    // 4. out[b] = (exp-scores[b] @ vtb[b]^T) / rsum  (1024 blocks; MINW=4)
    dim3 g3(H_ / 64, S_ / 128, B_);
    gemm_bt<64, 4, false, false, false, false, true><<<g3, 256, 0, stream>>>(
        sc,  S_, (long long)S_ * S_,
        vtb, S_, (long long)H_ * S_,
        nullptr, out, H_, (long long)S_ * H_, nullptr, rsum, S_, H_, S_, 1.0f);
}